// Round 23
// baseline (209.795 us; speedup 1.0000x reference)
//
#include <hip/hip_runtime.h>

#define N_ROWS 65536
#define NE 1024
#define ED 64
#define ERR_GAP 8e-5f

static const size_t OFF_ZQ = 1;
static const size_t OFF_ME = 1 + 4194304;
static const size_t OFF_IDX = OFF_ME + (size_t)N_ROWS * NE;
#define ME_FLOATS ((size_t)N_ROWS * NE)   // 67108864

// scratch: cbfrag in the z_q OUTPUT region (consumed by distfill before zq writes).
#define SC_CBF  0         // cbfrag: 131072 shorts
// d_ws: cnt at +8, e2 at +16 (4KB), partial at +4112 (8KB)

typedef __attribute__((ext_vector_type(8))) short short8v;
typedef __attribute__((ext_vector_type(4))) float f32x4;

__device__ __forceinline__ unsigned bf16_rne(float v) {
  unsigned u = __float_as_uint(v);
  return (u + 0x7FFFu + ((u >> 16) & 1u)) >> 16;
}

__device__ __forceinline__ void gld16(const void* g, void* l) {
  __builtin_amdgcn_global_load_lds(
      (const __attribute__((address_space(1))) void*)g,
      (__attribute__((address_space(3))) void*)l, 16, 0, 0);
}

// ---- fused: codebook split + e2 (bit-exact) + counter reset ----
__global__ __launch_bounds__(256) void k_e2cb(const float* __restrict__ cb,
                                              float* __restrict__ e2,
                                              short* __restrict__ cbfrag,
                                              int* __restrict__ cnt) {
  if (blockIdx.x == 0 && threadIdx.x == 0) *cnt = 0;   // re-zero every launch
  const int tid = blockIdx.x * 256 + threadIdx.x;
  const int ct = tid >> 6, lane = tid & 63;
  const int col = ct * 16 + (lane & 15);
  const int k0 = (lane >> 4) * 8;
  const float* __restrict__ ep = cb + (size_t)col * ED + k0;
  short* __restrict__ o = cbfrag + (size_t)ct * 2048 + lane * 8;
  #pragma unroll
  for (int ks = 0; ks < 2; ++ks) {
    short h[8], lo[8];
    #pragma unroll
    for (int i = 0; i < 8; ++i) {
      const float v = ep[ks * 32 + i];
      const unsigned hb = bf16_rne(v);
      const float res = v - __uint_as_float(hb << 16);
      h[i] = (short)hb; lo[i] = (short)bf16_rne(res);
    }
    *(short8v*)(o + (size_t)(0 * 2 + ks) * 512) = *(short8v*)h;
    *(short8v*)(o + (size_t)(1 * 2 + ks) * 512) = *(short8v*)lo;
  }
  if (threadIdx.x < 64) {
    const int j = blockIdx.x * 64 + threadIdx.x;
    const float* __restrict__ e = cb + (size_t)j * ED;
    float r[8];
    #pragma unroll
    for (int i = 0; i < 8; ++i) {
      float v = e[i]; float q = v * v;
      asm volatile("" : "+v"(q)); r[i] = q;
    }
    #pragma unroll
    for (int k = 1; k < 8; ++k)
      #pragma unroll
      for (int i = 0; i < 8; ++i) {
        float v = e[8 * k + i]; float q = v * v;
        asm volatile("" : "+v"(q)); r[i] += q;
      }
    e2[j] = ((r[0] + r[1]) + (r[2] + r[3])) + ((r[4] + r[5]) + (r[6] + r[7]));
  }
}

// ---- heterogeneous grid: blocks 0-1023 = distance (+inline rescore);
//      blocks 1024-3071 = zero-fill of the one-hot region (idxf-independent,
//      write-BW-bound -> overlaps dist's VALU/MFMA work as CUs free up) ----
__global__ __launch_bounds__(256, 4) void k_distfill(const float* __restrict__ z,
    const float* __restrict__ cb, const short* __restrict__ cbfrag,
    const float* __restrict__ e2g, float* __restrict__ idxf,
    float* __restrict__ me) {
  __shared__ float4 smem4[2320];                 // 37120 B
  if (blockIdx.x >= 1024) {                      // ---- fill role ----
    const size_t n4 = (ME_FLOATS - 3) >> 2;
    float4* __restrict__ p4 = reinterpret_cast<float4*>(me + 3);
    const size_t stride = (size_t)2048 * 256;
    const float4 zero4 = make_float4(0.f, 0.f, 0.f, 0.f);
    for (size_t i = (size_t)(blockIdx.x - 1024) * 256 + threadIdx.x; i < n4; i += stride)
      p4[i] = zero4;
    if (blockIdx.x == 1024 && threadIdx.x == 0) {
      me[0] = 0.f; me[1] = 0.f; me[2] = 0.f;
      me[ME_FLOATS - 1] = 0.f;
    }
    return;
  }
  // ---- dist role (r22's k_distX, verbatim) ----
  short* lBs = (short*)smem4;
  float* e2l = (float*)(smem4 + 2048);
  float* z2l = (float*)(smem4 + 2304);
  float (*lzf)[65] = (float(*)[65])smem4;
  int* candL = (int*)smem4;                      // post-loop overlay
  int* nfl   = (int*)smem4 + 512;

  const int t = threadIdx.x, w = t >> 6, lane = t & 63;
  const int row0 = blockIdx.x * 64;

  gld16(e2g + w * 256 + lane * 4, e2l + w * 256);

  const int rl = w * 16 + (lane & 15);
  const int n0 = row0 + rl;
  const int bb = n0 >> 10, hw = n0 & 1023;
  const float* __restrict__ zp = z + (size_t)bb * 65536 + hw;
  const int k0 = (lane >> 4) * 8;
  #pragma unroll
  for (int ks = 0; ks < 2; ++ks)
    #pragma unroll
    for (int i = 0; i < 8; ++i)
      lzf[ks * 32 + k0 + i][rl] = zp[(size_t)(ks * 32 + k0 + i) << 10];
  __syncthreads();

  short8v a[2][2];
  #pragma unroll
  for (int ks = 0; ks < 2; ++ks) {
    short h[8], lo[8];
    #pragma unroll
    for (int i = 0; i < 8; ++i) {
      const float v = lzf[ks * 32 + k0 + i][rl];
      const unsigned hb = bf16_rne(v);
      const float res = v - __uint_as_float(hb << 16);
      h[i] = (short)hb; lo[i] = (short)bf16_rne(res);
    }
    a[0][ks] = *(short8v*)h;
    a[1][ks] = *(short8v*)lo;
  }
  if (t < 64) {
    float r[8];
    #pragma unroll
    for (int i = 0; i < 8; ++i) {
      const float v = lzf[i][t];
      float q = v * v; asm volatile("" : "+v"(q)); r[i] = q;
    }
    #pragma unroll
    for (int k = 1; k < 8; ++k)
      #pragma unroll
      for (int i = 0; i < 8; ++i) {
        const float v = lzf[8 * k + i][t];
        float q = v * v; asm volatile("" : "+v"(q)); r[i] += q;
      }
    z2l[t] = ((r[0] + r[1]) + (r[2] + r[3])) + ((r[4] + r[5]) + (r[6] + r[7]));
  }
  __syncthreads();

  #pragma unroll
  for (int i = 0; i < 4; ++i) {
    const int s = w * 4 + i;
    gld16(cbfrag + s * 512 + lane * 8, lBs + s * 512);
  }
  float z2r[4];
  #pragma unroll
  for (int reg = 0; reg < 4; ++reg)
    z2r[reg] = z2l[w * 16 + (lane >> 4) * 4 + reg];
  float Tm1[4], Tm2[4], Tm3[4]; int Tb1[4], Tb2[4];
  #pragma unroll
  for (int reg = 0; reg < 4; ++reg) {
    Tm1[reg] = 1e30f; Tm2[reg] = 1e30f; Tm3[reg] = 1e30f;
    Tb1[reg] = 0; Tb2[reg] = 0;
  }
  __syncthreads();

  int buf = 0;
  for (int c = 0; c < 16; ++c) {
    if (c < 15) {
      #pragma unroll
      for (int i = 0; i < 4; ++i) {
        const int s = w * 4 + i;
        gld16(cbfrag + (size_t)(c + 1) * 8192 + s * 512 + lane * 8,
              lBs + (buf ^ 1) * 8192 + s * 512);
      }
    }
    #pragma unroll 1
    for (int ctl = 0; ctl < 4; ++ctl) {
      short8v bfr[2][2];
      #pragma unroll
      for (int hl = 0; hl < 2; ++hl)
        #pragma unroll
        for (int ks = 0; ks < 2; ++ks)
          bfr[hl][ks] = *(const short8v*)(lBs + buf * 8192 +
              (ctl * 4 + hl * 2 + ks) * 512 + lane * 8);

      f32x4 acc = (f32x4)(0.0f);
      // pairs (a_hl,b_hl): (h,h) (h,l) (l,h); ks inner — same order as r8-r22
      #pragma unroll
      for (int p = 0; p < 3; ++p) {
        const int pa = (p == 2) ? 1 : 0;
        const int pb = (p == 1) ? 1 : 0;
        #pragma unroll
        for (int ks = 0; ks < 2; ++ks)
          acc = __builtin_amdgcn_mfma_f32_16x16x32_bf16(a[pa][ks], bfr[pb][ks], acc, 0, 0, 0);
      }
      const int j = c * 64 + ctl * 16 + (lane & 15);
      const float e2v = e2l[j];
      #pragma unroll
      for (int reg = 0; reg < 4; ++reg) {
        const float dd = (z2r[reg] + e2v) - 2.0f * acc[reg];
        if (dd < Tm1[reg]) {
          Tm3[reg] = Tm2[reg]; Tm2[reg] = Tm1[reg]; Tb2[reg] = Tb1[reg];
          Tm1[reg] = dd; Tb1[reg] = j;
        } else if (dd < Tm2[reg]) {
          Tm3[reg] = Tm2[reg]; Tm2[reg] = dd; Tb2[reg] = j;
        } else if (dd < Tm3[reg]) {
          Tm3[reg] = dd;
        }
      }
    }
    __syncthreads();
    buf ^= 1;
  }

  #pragma unroll
  for (int reg = 0; reg < 4; ++reg) {
    float rm = Tm1[reg]; int ri = Tb1[reg];
    #pragma unroll
    for (int off = 1; off < 16; off <<= 1) {
      const float om = __shfl_xor(rm, off, 64);
      const int   oi = __shfl_xor(ri, off, 64);
      if (om < rm || (om == rm && oi < ri)) { rm = om; ri = oi; }
    }
    const float thr = rm + ERR_GAP;
    const bool c1 = (Tm1[reg] <= thr);
    const bool c2 = (Tm2[reg] <= thr);
    const bool c3 = (Tm3[reg] <= thr);
    const unsigned long long b1 = __ballot(c1);
    const unsigned long long b2 = __ballot(c2);
    const unsigned long long b3 = __ballot(c3);
    const int grp = lane >> 4;
    const unsigned m1m = (unsigned)((b1 >> (grp * 16)) & 0xFFFFull);
    const unsigned m2m = (unsigned)((b2 >> (grp * 16)) & 0xFFFFull);
    const unsigned m3m = (unsigned)((b3 >> (grp * 16)) & 0xFFFFull);
    const int n1 = __popc(m1m);
    const int ncand = n1 + __popc(m2m);
    const bool ovf = (m3m != 0u) || (ncand > 8);
    const int rowLocal = w * 16 + grp * 4 + reg;
    if (!ovf) {
      const unsigned below = (1u << (lane & 15)) - 1u;
      if (c1) candL[rowLocal * 8 + __popc(m1m & below)] = Tb1[reg];
      if (c2) candL[rowLocal * 8 + n1 + __popc(m2m & below)] = Tb2[reg];
    }
    if ((lane & 15) == 0) {
      const bool wrf = ovf || (ncand >= 2);
      nfl[rowLocal] = ovf ? 999 : (ncand >= 2 ? ncand : 0);
      if (!wrf) idxf[row0 + rowLocal] = (float)ri;
    }
  }
  __syncthreads();

  #pragma unroll 1
  for (int r = 0; r < 16; ++r) {
    const int rowLocal = w * 16 + r;
    const int fn = nfl[rowLocal];
    if (fn == 0) continue;
    const int n = row0 + rowLocal;
    const int b2 = n >> 10, hw2 = n & 1023;
    const float zv = z[(size_t)b2 * 65536 + ((size_t)lane << 10) + hw2];
    const float z2v = z2l[rowLocal];
    if (fn != 999) {
      const int ci = candL[rowLocal * 8 + (lane < fn ? lane : 0)];
      const float* __restrict__ e = cb + (size_t)ci * ED;
      float acl = 0.f;
      #pragma unroll 8
      for (int k = 0; k < ED; ++k)
        acl = fmaf(__shfl(zv, k, 64), e[k], acl);   // ascending k, bit-exact
      float d = (z2v + e2l[ci]) - 2.0f * acl;
      int bi = ci;
      if (lane >= fn) { d = 1e30f; bi = 0x7FFFFFFF; }
      #pragma unroll
      for (int off = 1; off < 8; off <<= 1) {
        const float om = __shfl_xor(d, off, 64);
        const int   oi = __shfl_xor(bi, off, 64);
        if (om < d || (om == d && oi < bi)) { d = om; bi = oi; }
      }
      if (lane == 0) idxf[n] = (float)bi;
    } else {
      float bm = 1e30f; int bi = 0;
      #pragma unroll 1
      for (int q = 0; q < 16; ++q) {
        const int j = lane * 16 + q;
        const float4* __restrict__ e4 = (const float4*)(cb + (size_t)j * ED);
        float acl = 0.f;
        #pragma unroll
        for (int p = 0; p < 16; ++p) {
          const float4 ee = e4[p];
          acl = fmaf(__shfl(zv, 4 * p + 0, 64), ee.x, acl);
          acl = fmaf(__shfl(zv, 4 * p + 1, 64), ee.y, acl);
          acl = fmaf(__shfl(zv, 4 * p + 2, 64), ee.z, acl);
          acl = fmaf(__shfl(zv, 4 * p + 3, 64), ee.w, acl);
        }
        const float d = (z2v + e2l[j]) - 2.0f * acl;
        if (d < bm) { bm = d; bi = j; }
      }
      #pragma unroll
      for (int off = 1; off < 64; off <<= 1) {
        const float om = __shfl_xor(bm, off, 64);
        const int   oi = __shfl_xor(bi, off, 64);
        if (om < bm || (om == bm && oi < bi)) { bm = om; bi = oi; }
      }
      if (lane == 0) idxf[n] = (float)bi;
    }
  }
}

// ---- z_q gather + hot-index write + loss partial + last-block loss reduce ----
__global__ __launch_bounds__(256) void k_zqhot(const float* __restrict__ z,
    const float* __restrict__ cb, const float* __restrict__ idxf,
    float* __restrict__ zq, float* __restrict__ partial, float* __restrict__ me,
    int* __restrict__ cnt, float* __restrict__ out0) {
  __shared__ float sh[4];
  __shared__ int isLast;
  float s = 0.f;
  #pragma unroll 1
  for (int it = 0; it < 8; ++it) {
    const int o = (it * 2048 + blockIdx.x) * 256 + threadIdx.x;
    const int b = o >> 16;
    const int d = (o >> 10) & 63;
    const int hw = o & 1023;
    const int n = (b << 10) + hw;
    const int idx = (int)idxf[n];
    const float v = cb[(size_t)idx * ED + d];
    zq[o] = v;
    if (d == 0) me[(size_t)n * NE + idx] = 1.0f;   // one hot per row (r15-proven)
    const float diff = z[o] - v;
    s = fmaf(diff, diff, s);
  }
  #pragma unroll
  for (int off = 32; off > 0; off >>= 1) s += __shfl_xor(s, off, 64);
  if ((threadIdx.x & 63) == 0) sh[threadIdx.x >> 6] = s;
  __syncthreads();
  if (threadIdx.x == 0) {
    partial[blockIdx.x] = (sh[0] + sh[1]) + (sh[2] + sh[3]);
    __threadfence();                               // publish partial
    const int old = atomicAdd(cnt, 1);             // device-scope
    isLast = (old == (int)gridDim.x - 1) ? 1 : 0;
  }
  __syncthreads();
  if (isLast) {                                    // deterministic: fixed-order sum
    __threadfence();                               // acquire others' partials
    const int t = threadIdx.x;
    double sd = 0.0;
    #pragma unroll
    for (int k = 0; k < 8; ++k) sd += (double)partial[t + (k << 8)];
    #pragma unroll
    for (int off = 32; off > 0; off >>= 1) sd += __shfl_xor(sd, off, 64);
    __shared__ double shd[4];
    if ((t & 63) == 0) shd[t >> 6] = sd;
    __syncthreads();
    if (t == 0)
      out0[0] = (float)(1.25 * ((shd[0] + shd[1]) + (shd[2] + shd[3])) / 4194304.0);
  }
}

extern "C" void kernel_launch(void* const* d_in, const int* in_sizes, int n_in,
                              void* d_out, int out_size, void* d_ws, size_t ws_size,
                              hipStream_t stream) {
  const float* z  = (const float*)d_in[0];
  const float* cb = (const float*)d_in[1];
  float* out  = (float*)d_out;
  float* zq   = out + OFF_ZQ;
  float* me   = out + OFF_ME;
  float* idxf = out + OFF_IDX;
  float* sbase = out + 4;
  short* cbfrag = (short*)(sbase + SC_CBF);
  int*   cnt     = (int*)((char*)d_ws + 8);
  float* e2      = (float*)((char*)d_ws + 16);
  float* partial = (float*)((char*)d_ws + 4112);

  k_e2cb<<<16, 256, 0, stream>>>(cb, e2, cbfrag, cnt);
  k_distfill<<<3072, 256, 0, stream>>>(z, cb, cbfrag, e2, idxf, me);
  k_zqhot<<<2048, 256, 0, stream>>>(z, cb, idxf, zq, partial, me, cnt, out);
}

// Round 24
// 164.370 us; speedup vs baseline: 1.2764x; 1.2764x over previous
//
#include <hip/hip_runtime.h>

#define N_ROWS 65536
#define NE 1024
#define ED 64
#define ERR_GAP 8e-5f

static const size_t OFF_ZQ = 1;
static const size_t OFF_ME = 1 + 4194304;
static const size_t OFF_IDX = OFF_ME + (size_t)N_ROWS * NE;
#define ME_FLOATS ((size_t)N_ROWS * NE)   // 67108864

// scratch: cbfrag in the z_q OUTPUT region (consumed by distX before zq writes).
#define SC_CBF  0         // cbfrag: 131072 shorts
// d_ws: e2 at +16 (4KB), partial at +4112 (8KB)

typedef __attribute__((ext_vector_type(8))) short short8v;
typedef __attribute__((ext_vector_type(4))) float f32x4;

__device__ __forceinline__ unsigned bf16_rne(float v) {
  unsigned u = __float_as_uint(v);
  return (u + 0x7FFFu + ((u >> 16) & 1u)) >> 16;
}

__device__ __forceinline__ void gld16(const void* g, void* l) {
  __builtin_amdgcn_global_load_lds(
      (const __attribute__((address_space(1))) void*)g,
      (__attribute__((address_space(3))) void*)l, 16, 0, 0);
}

// ---- fused: codebook split + e2 (bit-exact) ----
__global__ __launch_bounds__(256) void k_e2cb(const float* __restrict__ cb,
                                              float* __restrict__ e2,
                                              short* __restrict__ cbfrag) {
  const int tid = blockIdx.x * 256 + threadIdx.x;
  const int ct = tid >> 6, lane = tid & 63;
  const int col = ct * 16 + (lane & 15);
  const int k0 = (lane >> 4) * 8;
  const float* __restrict__ ep = cb + (size_t)col * ED + k0;
  short* __restrict__ o = cbfrag + (size_t)ct * 2048 + lane * 8;
  #pragma unroll
  for (int ks = 0; ks < 2; ++ks) {
    short h[8], lo[8];
    #pragma unroll
    for (int i = 0; i < 8; ++i) {
      const float v = ep[ks * 32 + i];
      const unsigned hb = bf16_rne(v);
      const float res = v - __uint_as_float(hb << 16);
      h[i] = (short)hb; lo[i] = (short)bf16_rne(res);
    }
    *(short8v*)(o + (size_t)(0 * 2 + ks) * 512) = *(short8v*)h;
    *(short8v*)(o + (size_t)(1 * 2 + ks) * 512) = *(short8v*)lo;
  }
  if (threadIdx.x < 64) {
    const int j = blockIdx.x * 64 + threadIdx.x;
    const float* __restrict__ e = cb + (size_t)j * ED;
    float r[8];
    #pragma unroll
    for (int i = 0; i < 8; ++i) {
      float v = e[i]; float q = v * v;
      asm volatile("" : "+v"(q)); r[i] = q;
    }
    #pragma unroll
    for (int k = 1; k < 8; ++k)
      #pragma unroll
      for (int i = 0; i < 8; ++i) {
        float v = e[8 * k + i]; float q = v * v;
        asm volatile("" : "+v"(q)); r[i] += q;
      }
    e2[j] = ((r[0] + r[1]) + (r[2] + r[3])) + ((r[4] + r[5]) + (r[6] + r[7]));
  }
}

// ---- fused: dist (MFMA) + top-3 + candidate emission + INLINE rescore ----
__global__ __launch_bounds__(256, 4) void k_distX(const float* __restrict__ z,
    const float* __restrict__ cb, const short* __restrict__ cbfrag,
    const float* __restrict__ e2g, float* __restrict__ idxf) {
  __shared__ float4 smem4[2320];                 // 37120 B
  short* lBs = (short*)smem4;
  float* e2l = (float*)(smem4 + 2048);
  float* z2l = (float*)(smem4 + 2304);
  float (*lzf)[65] = (float(*)[65])smem4;
  int* candL = (int*)smem4;                      // [64][8] ints, post-loop overlay
  int* nfl   = (int*)smem4 + 512;                // [64] ints

  const int t = threadIdx.x, w = t >> 6, lane = t & 63;
  const int row0 = blockIdx.x * 64;

  gld16(e2g + w * 256 + lane * 4, e2l + w * 256);

  const int rl = w * 16 + (lane & 15);
  const int n0 = row0 + rl;
  const int bb = n0 >> 10, hw = n0 & 1023;
  const float* __restrict__ zp = z + (size_t)bb * 65536 + hw;
  const int k0 = (lane >> 4) * 8;
  #pragma unroll
  for (int ks = 0; ks < 2; ++ks)
    #pragma unroll
    for (int i = 0; i < 8; ++i)
      lzf[ks * 32 + k0 + i][rl] = zp[(size_t)(ks * 32 + k0 + i) << 10];
  __syncthreads();

  short8v a[2][2];
  #pragma unroll
  for (int ks = 0; ks < 2; ++ks) {
    short h[8], lo[8];
    #pragma unroll
    for (int i = 0; i < 8; ++i) {
      const float v = lzf[ks * 32 + k0 + i][rl];
      const unsigned hb = bf16_rne(v);
      const float res = v - __uint_as_float(hb << 16);
      h[i] = (short)hb; lo[i] = (short)bf16_rne(res);
    }
    a[0][ks] = *(short8v*)h;
    a[1][ks] = *(short8v*)lo;
  }
  if (t < 64) {
    float r[8];
    #pragma unroll
    for (int i = 0; i < 8; ++i) {
      const float v = lzf[i][t];
      float q = v * v; asm volatile("" : "+v"(q)); r[i] = q;
    }
    #pragma unroll
    for (int k = 1; k < 8; ++k)
      #pragma unroll
      for (int i = 0; i < 8; ++i) {
        const float v = lzf[8 * k + i][t];
        float q = v * v; asm volatile("" : "+v"(q)); r[i] += q;
      }
    z2l[t] = ((r[0] + r[1]) + (r[2] + r[3])) + ((r[4] + r[5]) + (r[6] + r[7]));
  }
  __syncthreads();

  #pragma unroll
  for (int i = 0; i < 4; ++i) {
    const int s = w * 4 + i;
    gld16(cbfrag + s * 512 + lane * 8, lBs + s * 512);
  }
  float z2r[4];
  #pragma unroll
  for (int reg = 0; reg < 4; ++reg)
    z2r[reg] = z2l[w * 16 + (lane >> 4) * 4 + reg];
  float Tm1[4], Tm2[4], Tm3[4]; int Tb1[4], Tb2[4];
  #pragma unroll
  for (int reg = 0; reg < 4; ++reg) {
    Tm1[reg] = 1e30f; Tm2[reg] = 1e30f; Tm3[reg] = 1e30f;
    Tb1[reg] = 0; Tb2[reg] = 0;
  }
  __syncthreads();

  int buf = 0;
  for (int c = 0; c < 16; ++c) {
    if (c < 15) {
      #pragma unroll
      for (int i = 0; i < 4; ++i) {
        const int s = w * 4 + i;
        gld16(cbfrag + (size_t)(c + 1) * 8192 + s * 512 + lane * 8,
              lBs + (buf ^ 1) * 8192 + s * 512);
      }
    }
    #pragma unroll 1
    for (int ctl = 0; ctl < 4; ++ctl) {
      short8v bfr[2][2];
      #pragma unroll
      for (int hl = 0; hl < 2; ++hl)
        #pragma unroll
        for (int ks = 0; ks < 2; ++ks)
          bfr[hl][ks] = *(const short8v*)(lBs + buf * 8192 +
              (ctl * 4 + hl * 2 + ks) * 512 + lane * 8);

      f32x4 acc = (f32x4)(0.0f);
      // pairs (a_hl,b_hl): (h,h) (h,l) (l,h); ks inner — same order as r8-r22
      #pragma unroll
      for (int p = 0; p < 3; ++p) {
        const int pa = (p == 2) ? 1 : 0;
        const int pb = (p == 1) ? 1 : 0;
        #pragma unroll
        for (int ks = 0; ks < 2; ++ks)
          acc = __builtin_amdgcn_mfma_f32_16x16x32_bf16(a[pa][ks], bfr[pb][ks], acc, 0, 0, 0);
      }
      const int j = c * 64 + ctl * 16 + (lane & 15);
      const float e2v = e2l[j];
      #pragma unroll
      for (int reg = 0; reg < 4; ++reg) {
        const float dd = (z2r[reg] + e2v) - 2.0f * acc[reg];
        if (dd < Tm1[reg]) {
          Tm3[reg] = Tm2[reg]; Tm2[reg] = Tm1[reg]; Tb2[reg] = Tb1[reg];
          Tm1[reg] = dd; Tb1[reg] = j;
        } else if (dd < Tm2[reg]) {
          Tm3[reg] = Tm2[reg]; Tm2[reg] = dd; Tb2[reg] = j;
        } else if (dd < Tm3[reg]) {
          Tm3[reg] = dd;
        }
      }
    }
    __syncthreads();   // final iter: all lB reads done; lBs dead afterward
    buf ^= 1;
  }

  // epilogue: lex reduce; candidates -> LDS; flagged rows rescored below
  #pragma unroll
  for (int reg = 0; reg < 4; ++reg) {
    float rm = Tm1[reg]; int ri = Tb1[reg];
    #pragma unroll
    for (int off = 1; off < 16; off <<= 1) {
      const float om = __shfl_xor(rm, off, 64);
      const int   oi = __shfl_xor(ri, off, 64);
      if (om < rm || (om == rm && oi < ri)) { rm = om; ri = oi; }
    }
    const float thr = rm + ERR_GAP;
    const bool c1 = (Tm1[reg] <= thr);
    const bool c2 = (Tm2[reg] <= thr);
    const bool c3 = (Tm3[reg] <= thr);
    const unsigned long long b1 = __ballot(c1);
    const unsigned long long b2 = __ballot(c2);
    const unsigned long long b3 = __ballot(c3);
    const int grp = lane >> 4;
    const unsigned m1m = (unsigned)((b1 >> (grp * 16)) & 0xFFFFull);
    const unsigned m2m = (unsigned)((b2 >> (grp * 16)) & 0xFFFFull);
    const unsigned m3m = (unsigned)((b3 >> (grp * 16)) & 0xFFFFull);
    const int n1 = __popc(m1m);
    const int ncand = n1 + __popc(m2m);
    const bool ovf = (m3m != 0u) || (ncand > 8);
    const int rowLocal = w * 16 + grp * 4 + reg;
    if (!ovf) {
      const unsigned below = (1u << (lane & 15)) - 1u;
      if (c1) candL[rowLocal * 8 + __popc(m1m & below)] = Tb1[reg];
      if (c2) candL[rowLocal * 8 + n1 + __popc(m2m & below)] = Tb2[reg];
    }
    if ((lane & 15) == 0) {
      const bool wrf = ovf || (ncand >= 2);
      nfl[rowLocal] = ovf ? 999 : (ncand >= 2 ? ncand : 0);
      if (!wrf) idxf[row0 + rowLocal] = (float)ri;
    }
  }
  __syncthreads();

  // inline rescore: wave w handles its own rows w*16..w*16+15
  #pragma unroll 1
  for (int r = 0; r < 16; ++r) {
    const int rowLocal = w * 16 + r;
    const int fn = nfl[rowLocal];          // wave-uniform (same LDS addr)
    if (fn == 0) continue;
    const int n = row0 + rowLocal;
    const int b2 = n >> 10, hw2 = n & 1023;
    const float zv = z[(size_t)b2 * 65536 + ((size_t)lane << 10) + hw2];  // lane k = z_k
    const float z2v = z2l[rowLocal];
    if (fn != 999) {
      // all 64 lanes active through the shfl chain (clamped cand slot)
      const int ci = candL[rowLocal * 8 + (lane < fn ? lane : 0)];
      const float* __restrict__ e = cb + (size_t)ci * ED;
      float acl = 0.f;
      #pragma unroll 8
      for (int k = 0; k < ED; ++k)
        acl = fmaf(__shfl(zv, k, 64), e[k], acl);   // ascending k, bit-exact
      float d = (z2v + e2l[ci]) - 2.0f * acl;
      int bi = ci;
      if (lane >= fn) { d = 1e30f; bi = 0x7FFFFFFF; }  // mask AFTER shfls
      #pragma unroll
      for (int off = 1; off < 8; off <<= 1) {
        const float om = __shfl_xor(d, off, 64);
        const int   oi = __shfl_xor(bi, off, 64);
        if (om < d || (om == d && oi < bi)) { d = om; bi = oi; }
      }
      if (lane == 0) idxf[n] = (float)bi;
    } else {
      // full rescan (rare): 16 codes/lane, float4 loads, ascending-k chain
      float bm = 1e30f; int bi = 0;
      #pragma unroll 1
      for (int q = 0; q < 16; ++q) {
        const int j = lane * 16 + q;
        const float4* __restrict__ e4 = (const float4*)(cb + (size_t)j * ED);
        float acl = 0.f;
        #pragma unroll
        for (int p = 0; p < 16; ++p) {
          const float4 ee = e4[p];
          acl = fmaf(__shfl(zv, 4 * p + 0, 64), ee.x, acl);
          acl = fmaf(__shfl(zv, 4 * p + 1, 64), ee.y, acl);
          acl = fmaf(__shfl(zv, 4 * p + 2, 64), ee.z, acl);
          acl = fmaf(__shfl(zv, 4 * p + 3, 64), ee.w, acl);
        }
        const float d = (z2v + e2l[j]) - 2.0f * acl;
        if (d < bm) { bm = d; bi = j; }
      }
      #pragma unroll
      for (int off = 1; off < 64; off <<= 1) {
        const float om = __shfl_xor(bm, off, 64);
        const int   oi = __shfl_xor(bi, off, 64);
        if (om < bm || (om == bm && oi < bi)) { bm = om; bi = oi; }
      }
      if (lane == 0) idxf[n] = (float)bi;
    }
  }
}

// ---- z_q gather + loss partials ----
__global__ __launch_bounds__(256) void k_zq(const float* __restrict__ z,
    const float* __restrict__ cb, const float* __restrict__ idxf,
    float* __restrict__ zq, float* __restrict__ partial) {
  float s = 0.f;
  #pragma unroll 1
  for (int it = 0; it < 8; ++it) {
    const int o = (it * 2048 + blockIdx.x) * 256 + threadIdx.x;
    const int b = o >> 16;
    const int d = (o >> 10) & 63;
    const int hw = o & 1023;
    const int n = (b << 10) + hw;
    const int idx = (int)idxf[n];
    const float v = cb[(size_t)idx * ED + d];
    zq[o] = v;
    const float diff = z[o] - v;
    s = fmaf(diff, diff, s);
  }
  #pragma unroll
  for (int off = 32; off > 0; off >>= 1) s += __shfl_xor(s, off, 64);
  __shared__ float sh[4];
  if ((threadIdx.x & 63) == 0) sh[threadIdx.x >> 6] = s;
  __syncthreads();
  if (threadIdx.x == 0)
    partial[blockIdx.x] = (sh[0] + sh[1]) + (sh[2] + sh[3]);
}

// ---- one-hot writer (fill+hot in ONE pass, per-row LDS-hoisted idx) + loss ----
__global__ __launch_bounds__(256) void k_onehot(const float* __restrict__ idxf,
    const float* __restrict__ partial, float* __restrict__ me,
    float* __restrict__ out0) {
  __shared__ int idxL[32];
  const int t = threadIdx.x;
  const int n0 = blockIdx.x * 32;
  if (t < 32) idxL[t] = (int)idxf[n0 + t];
  __syncthreads();
  float* __restrict__ base = me + (size_t)n0 * 1024;   // float-offset ≡1 mod 4
  float4* __restrict__ p4 = (float4*)(base + 3);       // 16B-aligned
  #pragma unroll 1
  for (int s = t; s < 8191; s += 256) {                // floats 3..32766
    const int f0 = 3 + 4 * s;
    const int row = f0 >> 10;
    const int col0 = f0 & 1023;
    float4 v;
    if (col0 <= 1020) {
      const int idx = idxL[row];
      v.x = (col0 == idx)     ? 1.0f : 0.0f;
      v.y = (col0 + 1 == idx) ? 1.0f : 0.0f;
      v.z = (col0 + 2 == idx) ? 1.0f : 0.0f;
      v.w = (col0 + 3 == idx) ? 1.0f : 0.0f;
    } else {                                           // col0 == 1023: spans rows
      v.x = (idxL[row] == 1023)    ? 1.0f : 0.0f;
      v.y = (idxL[row + 1] == 0)   ? 1.0f : 0.0f;
      v.z = (idxL[row + 1] == 1)   ? 1.0f : 0.0f;
      v.w = (idxL[row + 1] == 2)   ? 1.0f : 0.0f;
    }
    p4[s] = v;
  }
  if (t == 0) {                                        // strays: floats 0,1,2,32767
    base[0] = (idxL[0] == 0) ? 1.0f : 0.0f;
    base[1] = (idxL[0] == 1) ? 1.0f : 0.0f;
    base[2] = (idxL[0] == 2) ? 1.0f : 0.0f;
    base[32767] = (idxL[31] == 1023) ? 1.0f : 0.0f;
  }
  if (blockIdx.x == 0) {                               // fused loss reduce
    double sd = 0.0;
    #pragma unroll
    for (int k = 0; k < 8; ++k) sd += (double)partial[t + (k << 8)];
    #pragma unroll
    for (int off = 32; off > 0; off >>= 1) sd += __shfl_xor(sd, off, 64);
    __shared__ double shd[4];
    if ((t & 63) == 0) shd[t >> 6] = sd;
    __syncthreads();
    if (t == 0)
      out0[0] = (float)(1.25 * ((shd[0] + shd[1]) + (shd[2] + shd[3])) / 4194304.0);
  }
}

extern "C" void kernel_launch(void* const* d_in, const int* in_sizes, int n_in,
                              void* d_out, int out_size, void* d_ws, size_t ws_size,
                              hipStream_t stream) {
  const float* z  = (const float*)d_in[0];
  const float* cb = (const float*)d_in[1];
  float* out  = (float*)d_out;
  float* zq   = out + OFF_ZQ;
  float* me   = out + OFF_ME;
  float* idxf = out + OFF_IDX;
  float* sbase = out + 4;
  short* cbfrag = (short*)(sbase + SC_CBF);
  float* e2      = (float*)((char*)d_ws + 16);
  float* partial = (float*)((char*)d_ws + 4112);

  k_e2cb<<<16, 256, 0, stream>>>(cb, e2, cbfrag);
  k_distX<<<1024, 256, 0, stream>>>(z, cb, cbfrag, e2, idxf);
  k_zq<<<2048, 256, 0, stream>>>(z, cb, idxf, zq, partial);
  k_onehot<<<2048, 256, 0, stream>>>(idxf, partial, me, out);
}